// Round 1
// baseline (546.698 us; speedup 1.0000x reference)
//
#include <hip/hip_runtime.h>
#include <math.h>

#define ETA 0.5f
#define KAPPA 0.1f
#define NUM_SAMPLES 100
#define DIM 1024
#define BATCH 1024

// One block per batch row. Streams 100*1024 f32 of perturbations (float4,
// coalesced), reduces sum-of-squares; also row sum-sq of residue and
// constraint_manifold. Memory-bound: ~428 MB total -> ~68 us floor @6.3TB/s.
__global__ __launch_bounds__(256) void soliton_kernel(
    const float* __restrict__ residue,
    const float* __restrict__ cmani,
    const float* __restrict__ pert,
    float* __restrict__ out)
{
    const int b   = blockIdx.x;
    const int tid = threadIdx.x;

    // --- perturbation sum of squares over [NUM_SAMPLES, DIM] ---
    const float4* p4 = (const float4*)(pert + (size_t)b * NUM_SAMPLES * DIM);
    const int n4 = NUM_SAMPLES * DIM / 4; // 25600 float4 per row
    float psum = 0.f;
    for (int i = tid; i < n4; i += 256) {
        float4 v = p4[i];
        psum += v.x * v.x + v.y * v.y + v.z * v.z + v.w * v.w;
    }

    // --- residue energy: 1024 floats = 256 float4, one per thread ---
    const float4* r4 = (const float4*)(residue + (size_t)b * DIM);
    float4 rv = r4[tid];
    float esum = rv.x * rv.x + rv.y * rv.y + rv.z * rv.z + rv.w * rv.w;

    // --- constraint manifold sum-sq ---
    const float4* c4 = (const float4*)(cmani + (size_t)b * DIM);
    float4 cv = c4[tid];
    float csum = cv.x * cv.x + cv.y * cv.y + cv.z * cv.z + cv.w * cv.w;

    // --- wave (64-lane) shuffle reduction of all three ---
    #pragma unroll
    for (int off = 32; off > 0; off >>= 1) {
        psum += __shfl_down(psum, off, 64);
        esum += __shfl_down(esum, off, 64);
        csum += __shfl_down(csum, off, 64);
    }
    __shared__ float sp[4], se[4], sc[4];
    const int wave = tid >> 6;
    if ((tid & 63) == 0) { sp[wave] = psum; se[wave] = esum; sc[wave] = csum; }
    __syncthreads();

    if (tid == 0) {
        float P = sp[0] + sp[1] + sp[2] + sp[3];
        float E = se[0] + se[1] + se[2] + se[3];
        float C = sc[0] + sc[1] + sc[2] + sc[3];

        float dispersion     = P / (float)NUM_SAMPLES;   // mean over samples of per-sample sum_d
        float scale          = sqrtf(C);                 // ||constraint_manifold||
        float energy_density = E / (scale + 1e-8f);
        float localization   = (E > 0.f) ? (ETA / (energy_density + 1e-8f)) : scale;
        float ratio          = dispersion / (localization + 1e-8f);

        out[0 * BATCH + b] = (ratio < KAPPA) ? 1.0f : 0.0f;  // is_soliton
        out[1 * BATCH + b] = dispersion;
        out[2 * BATCH + b] = localization;
        out[3 * BATCH + b] = ratio;
    }
}

extern "C" void kernel_launch(void* const* d_in, const int* in_sizes, int n_in,
                              void* d_out, int out_size, void* d_ws, size_t ws_size,
                              hipStream_t stream) {
    const float* residue = (const float*)d_in[0];
    const float* cmani   = (const float*)d_in[1];
    const float* pert    = (const float*)d_in[2];
    float* out = (float*)d_out;
    soliton_kernel<<<BATCH, 256, 0, stream>>>(residue, cmani, pert, out);
}

// Round 2
// 539.916 us; speedup vs baseline: 1.0126x; 1.0126x over previous
//
#include <hip/hip_runtime.h>
#include <math.h>

#define ETA 0.5f
#define KAPPA 0.1f
#define NUM_SAMPLES 100
#define DIM 1024
#define BATCH 1024
#define TPB 512   // 8 waves/block; 1024 blocks -> 2 blocks/CU -> 32 waves/CU (full)

// One block per batch row. Streams 100*1024 f32 of perturbations (float4,
// coalesced), reduces sum-of-squares; also row sum-sq of residue and
// constraint_manifold. Memory-bound: ~428 MB total -> ~68 us floor @6.3TB/s.
// R2: 512-thread blocks for full 32-wave/CU occupancy + dual accumulators
// (2 independent float4 loads in flight per thread) to cover ~900cy HBM latency.
__global__ __launch_bounds__(TPB) void soliton_kernel(
    const float* __restrict__ residue,
    const float* __restrict__ cmani,
    const float* __restrict__ pert,
    float* __restrict__ out)
{
    const int b   = blockIdx.x;
    const int tid = threadIdx.x;

    // --- perturbation sum of squares over [NUM_SAMPLES, DIM] ---
    const float4* p4 = (const float4*)(pert + (size_t)b * NUM_SAMPLES * DIM);
    // n4 = 25600 float4 per row; per thread: 50 loads = 25 iterations x 2
    float psum0 = 0.f, psum1 = 0.f;
    #pragma unroll 5
    for (int i = tid; i < NUM_SAMPLES * DIM / 4; i += 2 * TPB) {
        float4 a = p4[i];
        float4 c = p4[i + TPB];
        psum0 += a.x * a.x + a.y * a.y + a.z * a.z + a.w * a.w;
        psum1 += c.x * c.x + c.y * c.y + c.z * c.z + c.w * c.w;
    }
    float psum = psum0 + psum1;

    // --- residue energy: 1024 floats = 512 float2, one per thread ---
    const float2* r2 = (const float2*)(residue + (size_t)b * DIM);
    float2 rv = r2[tid];
    float esum = rv.x * rv.x + rv.y * rv.y;

    // --- constraint manifold sum-sq ---
    const float2* c2 = (const float2*)(cmani + (size_t)b * DIM);
    float2 cv = c2[tid];
    float csum = cv.x * cv.x + cv.y * cv.y;

    // --- wave (64-lane) shuffle reduction of all three ---
    #pragma unroll
    for (int off = 32; off > 0; off >>= 1) {
        psum += __shfl_down(psum, off, 64);
        esum += __shfl_down(esum, off, 64);
        csum += __shfl_down(csum, off, 64);
    }
    __shared__ float sp[TPB / 64], se[TPB / 64], sc[TPB / 64];
    const int wave = tid >> 6;
    if ((tid & 63) == 0) { sp[wave] = psum; se[wave] = esum; sc[wave] = csum; }
    __syncthreads();

    if (tid == 0) {
        float P = 0.f, E = 0.f, C = 0.f;
        #pragma unroll
        for (int w = 0; w < TPB / 64; ++w) { P += sp[w]; E += se[w]; C += sc[w]; }

        float dispersion     = P / (float)NUM_SAMPLES;   // mean over samples of per-sample sum_d
        float scale          = sqrtf(C);                 // ||constraint_manifold||
        float energy_density = E / (scale + 1e-8f);
        float localization   = (E > 0.f) ? (ETA / (energy_density + 1e-8f)) : scale;
        float ratio          = dispersion / (localization + 1e-8f);

        out[0 * BATCH + b] = (ratio < KAPPA) ? 1.0f : 0.0f;  // is_soliton
        out[1 * BATCH + b] = dispersion;
        out[2 * BATCH + b] = localization;
        out[3 * BATCH + b] = ratio;
    }
}

extern "C" void kernel_launch(void* const* d_in, const int* in_sizes, int n_in,
                              void* d_out, int out_size, void* d_ws, size_t ws_size,
                              hipStream_t stream) {
    const float* residue = (const float*)d_in[0];
    const float* cmani   = (const float*)d_in[1];
    const float* pert    = (const float*)d_in[2];
    float* out = (float*)d_out;
    soliton_kernel<<<BATCH, TPB, 0, stream>>>(residue, cmani, pert, out);
}